// Round 3
// baseline (113.277 us; speedup 1.0000x reference)
//
#include <hip/hip_runtime.h>

// Fused iterated 3x3 median blur (edge-replicate), up to 9 iterations.
//
// R3 = R2 with the T==0 copy-loop bound fixed (100 -> 400; R2 left 3/4 of
// t=0 tiles at memset-zero, absmax 5.4 = max|N(0,1)| signature).
//
// Design: WAVE-AUTONOMOUS tiles. One wave (64 threads) per block owns a
// 40x40 output tile + 9 halo = 58x58 LDS (13.5 KB). Each lane owns a 7x7
// patch of the compute region [1,56]^2 kept in registers across
// iterations; per iteration only the 32-cell halo ring is read from LDS
// and the 24-cell patch perimeter written back. ALL ring exchange is
// intra-wave, so the two per-iteration __syncthreads() are single-wave
// barriers (no inter-wave lock-step, no cross-wave barrier drain).
// ~10 independent waves/CU (LDS-limited) hide each other's latency.
// Validity shrinks 1 cell/iter: state-k valid on [k,57-k]^2, k<=9 ->
// [9,48]^2 = exactly the 40x40 output. Image-edge replicate pads are
// register fixups in pad-owning lanes (row fix then col fix -> corners
// exact); ring writes then publish pad values to LDS.
// Grid: 13x13 tiles of 40 (520>=512; edge tiles store-clamped) x 32 batches.

#define TD 58
#define OW 40
#define P  7
#define RAD 9
#define NT 64

__device__ __forceinline__ float min3f(float a, float b, float c) { return fminf(fminf(a, b), c); }
__device__ __forceinline__ float max3f(float a, float b, float c) { return fmaxf(fmaxf(a, b), c); }
__device__ __forceinline__ float med3f(float a, float b, float c) { return __builtin_amdgcn_fmed3f(a, b, c); }

__global__ __launch_bounds__(NT, 3) void median_fused_kernel(
    const float* __restrict__ src, float* __restrict__ dst,
    const int* __restrict__ t)
{
    __shared__ float buf[TD * TD];

    const int b   = blockIdx.y;
    const int ty  = blockIdx.x / 13;
    const int tx  = blockIdx.x - ty * 13;
    const int y0  = ty * OW;
    const int x0  = tx * OW;
    const int tid = threadIdx.x;
    const float* img  = src + (b << 18);
    float*       outb = dst + (b << 18);

    int T = t[b];
    T = min(max(T, 0), 9);

    if (T == 0) {                       // straight vector copy, no LDS
        for (int idx = tid; idx < 400; idx += NT) {   // 40 rows x 10 float4
            int row = idx / 10, c4 = idx - row * 10;
            int gy = y0 + row, gx = x0 + (c4 << 2);
            if (gy < 512 && gx < 512)
                *(float4*)&outb[(gy << 9) + gx] =
                    *(const float4*)&img[(gy << 9) + gx];
        }
        return;
    }

    // ---- load 58x58 halo tile, clamped (= replicate-padded image) ----
    for (int i = tid; i < TD * TD; i += NT) {
        int r = i / TD, c = i - r * TD;
        int gy = min(max(y0 - RAD + r, 0), 511);
        int gx = min(max(x0 - RAD + c, 0), 511);
        buf[i] = img[(gy << 9) + gx];
    }

    // lane -> 7x7 patch of compute region [1,56]^2
    const int ptx = tid & 7;            // 8 col groups x 7
    const int pty = tid >> 3;           // 8 row groups x 7
    const int ub  = 1 + P * pty;        // patch rows [ub, ub+6]
    const int vb  = 1 + P * ptx;        // patch cols [vb, vb+6]

    // pad-owning lanes (tile row r <-> image row y0-9+r):
    //  y0==0  : image row 0 = r=9 (pty=1,i=1); pad r=8 -> i=0 <- i=1
    //  y0==480: image row 511 = r=40 (pty=5,i=4); pad r=41 -> i=5 <- i=4
    //  cols symmetric with ptx / x0.
    const bool padTop = (y0 == 0)   && (pty == 1);
    const bool padBot = (y0 == 480) && (pty == 5);
    const bool padLft = (x0 == 0)   && (ptx == 1);
    const bool padRgt = (x0 == 480) && (ptx == 5);

    __syncthreads();                    // single-wave: near-free

    // preload own 7x7 patch (state 0) into registers
    float stage[49];
    #pragma unroll
    for (int i = 0; i < 7; ++i)
        #pragma unroll
        for (int j = 0; j < 7; ++j)
            stage[i * 7 + j] = buf[(ub + i) * TD + vb + j];

    for (int k = 0; k < T; ++k) {
        float A[9], Br[9], C[9];
        // window row ub-1: all 9 from LDS (neighbor ring / static boundary)
        {
            const float* p = &buf[(ub - 1) * TD + (vb - 1)];
            #pragma unroll
            for (int j = 0; j < 9; ++j) A[j] = p[j];
        }
        // window row ub: edges from LDS, middle from stage row 0
        Br[0] = buf[ub * TD + (vb - 1)];
        #pragma unroll
        for (int j = 0; j < 7; ++j) Br[1 + j] = stage[j];
        Br[8] = buf[ub * TD + (vb + 7)];

        #pragma unroll
        for (int i = 0; i < 7; ++i) {
            if (i < 6) {                // rows ub+1..ub+6: edges LDS, mid regs
                C[0] = buf[(ub + 1 + i) * TD + (vb - 1)];
                #pragma unroll
                for (int j = 0; j < 7; ++j) C[1 + j] = stage[(i + 1) * 7 + j];
                C[8] = buf[(ub + 1 + i) * TD + (vb + 7)];
            } else {                    // row ub+7: all 9 from LDS
                const float* p = &buf[(ub + 7) * TD + (vb - 1)];
                #pragma unroll
                for (int j = 0; j < 9; ++j) C[j] = p[j];
            }
            float lo[9], mi[9], hi[9];
            #pragma unroll
            for (int j = 0; j < 9; ++j) {
                lo[j] = min3f(A[j], Br[j], C[j]);
                mi[j] = med3f(A[j], Br[j], C[j]);
                hi[j] = max3f(A[j], Br[j], C[j]);
            }
            // in-place: old row i is in Br; row i+1 already consumed into C
            #pragma unroll
            for (int j = 0; j < 7; ++j)
                stage[i * 7 + j] = med3f(max3f(lo[j], lo[j+1], lo[j+2]),
                                         med3f(mi[j], mi[j+1], mi[j+2]),
                                         min3f(hi[j], hi[j+1], hi[j+2]));
            #pragma unroll
            for (int j = 0; j < 9; ++j) { A[j] = Br[j]; Br[j] = C[j]; }
        }

        // register pad fixups (row fix first, then col fix -> corners exact)
        if (padTop) {
            #pragma unroll
            for (int j = 0; j < 7; ++j) stage[j] = stage[7 + j];
        }
        if (padBot) {
            #pragma unroll
            for (int j = 0; j < 7; ++j) stage[35 + j] = stage[28 + j];
        }
        if (padLft) {
            #pragma unroll
            for (int i = 0; i < 7; ++i) stage[i * 7 + 0] = stage[i * 7 + 1];
        }
        if (padRgt) {
            #pragma unroll
            for (int i = 0; i < 7; ++i) stage[i * 7 + 5] = stage[i * 7 + 4];
        }

        __syncthreads();                // all ring reads of state k done (WAR)

        if (k == T - 1) {               // final: write all 49 for store phase
            #pragma unroll
            for (int i = 0; i < 7; ++i)
                #pragma unroll
                for (int j = 0; j < 7; ++j)
                    buf[(ub + i) * TD + vb + j] = stage[i * 7 + j];
        } else {                        // write the 24-cell patch perimeter
            #pragma unroll
            for (int j = 0; j < 7; ++j) {
                buf[ub * TD + vb + j]       = stage[j];
                buf[(ub + 6) * TD + vb + j] = stage[42 + j];
            }
            #pragma unroll
            for (int i = 1; i < 6; ++i) {
                buf[(ub + i) * TD + vb]     = stage[i * 7];
                buf[(ub + i) * TD + vb + 6] = stage[i * 7 + 6];
            }
        }

        __syncthreads();                // new ring visible (RAW)
    }

    // ---- store 40x40 output tile, float4 stores, clamped for edge tiles ----
    for (int idx = tid; idx < 400; idx += NT) {       // 40 rows x 10 float4
        int row = idx / 10, c4 = idx - row * 10;
        int gy = y0 + row, gx = x0 + (c4 << 2);
        if (gy < 512 && gx < 512) {
            const float* s = &buf[(RAD + row) * TD + RAD + (c4 << 2)];
            float4 v = { s[0], s[1], s[2], s[3] };
            *(float4*)&outb[(gy << 9) + gx] = v;
        }
    }
}

extern "C" void kernel_launch(void* const* d_in, const int* in_sizes, int n_in,
                              void* d_out, int out_size, void* d_ws, size_t ws_size,
                              hipStream_t stream) {
    const float* x   = (const float*)d_in[0];
    const int*   t   = (const int*)d_in[1];
    float*       out = (float*)d_out;

    dim3 block(NT);
    dim3 grid(169, 32);   // 13x13 tiles of 40 x 32 batches
    median_fused_kernel<<<grid, block, 0, stream>>>(x, out, t);
}